// Round 4
// baseline (700.720 us; speedup 1.0000x reference)
//
#include <hip/hip_runtime.h>
#include <math.h>

// B=8, Cin=256, H=W=128, RC=128, NC=12, HD=64, NL=3, E=132
#define BNS_F 0.9999950000374998f

typedef short short8 __attribute__((ext_vector_type(8)));   // 8 bf16 (4 VGPRs)
typedef float f32x4 __attribute__((ext_vector_type(4)));    // MFMA C/D frag
typedef __attribute__((address_space(3))) void lds_void;
typedef const __attribute__((address_space(1))) void glb_void;

__device__ __forceinline__ unsigned short f2bf(float f) {
    unsigned u = __builtin_bit_cast(unsigned, f);
    unsigned r = (u + 0x7fffu + ((u >> 16) & 1u)) >> 16;   // RNE
    return (unsigned short)r;
}
__device__ __forceinline__ float bf2f(unsigned short h) {
    unsigned u = ((unsigned)h) << 16;
    return __builtin_bit_cast(float, u);
}

// =====================================================================
// convert features fp32 [b][ic][px] -> bf16 pixel-major [b][px][ic]
// =====================================================================
__global__ __launch_bounds__(256) void convert_feat(
    const float* __restrict__ feat, unsigned short* __restrict__ Fbt)
{
    __shared__ unsigned short sb[64 * 270];
    int b = blockIdx.x >> 8;
    int px0 = (blockIdx.x & 255) * 64;
    int t = threadIdx.x, l = t & 63, w = t >> 6;

    for (int r = 0; r < 64; ++r) {
        int ic = r * 4 + w;
        float v = feat[((size_t)(b * 256 + ic)) * 16384 + px0 + l];
        sb[l * 270 + ic] = f2bf(v);
    }
    __syncthreads();

    uint4* dst = (uint4*)(Fbt + ((size_t)(b * 16384 + px0)) * 256);
    #pragma unroll
    for (int k = 0; k < 8; ++k) {
        int idx = k * 256 + t;          // uint4 index in [0,2048)
        int px = idx >> 5, piece = idx & 31;
        dst[idx] = *(const uint4*)(sb + px * 270 + piece * 8);
    }
}

// =====================================================================
// reorg W_rpn[oc][ic][tap] fp32 -> Wr[tap][oc][ic] bf16
// =====================================================================
__global__ __launch_bounds__(256) void reorg_w(
    const float* __restrict__ Wrpn, unsigned short* __restrict__ Wr)
{
    int oc = blockIdx.x;            // 128
    int ic = threadIdx.x;           // 256
    const float* src = Wrpn + ((size_t)oc * 256 + ic) * 9;
    #pragma unroll
    for (int tap = 0; tap < 9; ++tap)
        Wr[((size_t)tap * 128 + oc) * 256 + ic] = f2bf(src[tap]);
}

// =====================================================================
// masks = (maxpool3x3(seg) > 0.5), mask_sum[b,c]
// =====================================================================
__global__ __launch_bounds__(128) void masks_kernel(
    const float* __restrict__ seg, float* __restrict__ masks,
    float* __restrict__ mask_sum)
{
    int bid = blockIdx.x;
    int h = bid & 127;
    int c = (bid >> 7) % 12;
    int b = bid / (128 * 12);
    int px = threadIdx.x;

    const float* s = seg + ((size_t)(b * 12 + c) * 128) * 128;
    float m = -INFINITY;
    #pragma unroll
    for (int dy = -1; dy <= 1; ++dy) {
        int y = h + dy;
        if (y < 0 || y > 127) continue;
        #pragma unroll
        for (int dx = -1; dx <= 1; ++dx) {
            int x = px + dx;
            if (x < 0 || x > 127) continue;
            m = fmaxf(m, s[y * 128 + x]);
        }
    }
    float v = (m > 0.5f) ? 1.0f : 0.0f;
    masks[((size_t)(b * 12 + c) * 128 + h) * 128 + px] = v;

    float cnt = v;
    #pragma unroll
    for (int off = 1; off < 64; off <<= 1) cnt += __shfl_xor(cnt, off, 64);
    if ((threadIdx.x & 63) == 0) atomicAdd(&mask_sum[b * 12 + c], cnt);
}

// =====================================================================
// MFMA implicit-GEMM conv + fused 1x1 + masked sums.
// T4 schedule: counted vmcnt + raw barriers. Per chunk s:
//   [A-loads(s):18] [stage(s+1):4] s_waitcnt vmcnt(4) s_barrier
//   [ds_read + MFMA on buf(s)]    s_barrier
// FIFO queue at the waitcnt = [stage(s):4][A(s):18][stage(s+1):4], so
// vmcnt(4) completes chunk-s data while stage(s+1) stays in flight
// through the barriers and the whole MFMA phase.
// =====================================================================
#define SWZ(col) (((col) >> 1) & 3)
#define BUF_BYTES 24960   // 1560 chunks * 16B (3 rows * 130 cols * 4 slots)

__global__ __launch_bounds__(512) void conv_node_kernel(
    const unsigned short* __restrict__ Fbt, const unsigned short* __restrict__ Wr,
    const float* __restrict__ brpn, const float* __restrict__ Wnode,
    const float* __restrict__ bnode, const float* __restrict__ masks,
    const float* __restrict__ zero16, float* __restrict__ masked_sum)
{
    __shared__ __align__(16) unsigned char lds[49920];  // 2 staging bufs; epilogue reuses

    // XCD swizzle: nwg=1024 (divisible by 8)
    int wg = blockIdx.x;
    int bid = (wg & 7) * 128 + (wg >> 3);
    int h = bid & 127, b = bid >> 7;

    int t = threadIdx.x;
    int lane = t & 63;
    int wv = __builtin_amdgcn_readfirstlane(t >> 6);  // 0..7 wave-uniform
    int mg = wv >> 1;        // oc0 = mg*32
    int ng = wv & 1;         // px0 = ng*64
    int kg = lane >> 4;      // 0..3
    int ln15 = lane & 15;

    f32x4 acc[2][4];
    #pragma unroll
    for (int i = 0; i < 2; ++i)
        #pragma unroll
        for (int j = 0; j < 4; ++j) acc[i][j] = (f32x4){0.f, 0.f, 0.f, 0.f};

    const size_t fb_base = (size_t)b * 16384 * 256;

    // 4 wave-instructions per wave, uniform: rounds 0-2 = 512 chunks each,
    // round 3 = 24 halo chunks spread 3 per wave (lanes 0-2).
    auto stage = [&](int bsel, int ic0) {
        #pragma unroll
        for (int r = 0; r < 4; ++r) {
            int c      = (r < 3) ? (r * 512 + t) : (1536 + wv * 3 + lane);
            bool act   = (r < 3) || (lane < 3);
            unsigned ldsbase = (unsigned)bsel * BUF_BYTES
                + (unsigned)((r < 3) ? (r * 512 + wv * 64) : (1536 + wv * 3)) * 16;
            if (act) {
                int sp = c & 3, cr = c >> 2;
                int col = cr % 130, row = cr / 130;
                int sl = (sp - SWZ(col)) & 3;
                int y = h - 1 + row, x = col - 1;
                const void* gsrc = ((unsigned)y < 128u && (unsigned)x < 128u)
                    ? (const void*)(Fbt + fb_base + (size_t)(y * 128 + x) * 256
                                    + ic0 + sl * 8)
                    : (const void*)zero16;
                __builtin_amdgcn_global_load_lds(
                    (glb_void*)gsrc, (lds_void*)(lds + ldsbase), 16, 0, 0);
            }
        }
    };

    stage(0, 0);   // Q: [S0:4]

    for (int s = 0; s < 8; ++s) {
        int ic0 = s * 32;

        // ---- A-fragments for chunk s (before stage(s+1): FIFO order) ----
        short8 a0[9], a1[9];
        #pragma unroll
        for (int tap = 0; tap < 9; ++tap) {
            const unsigned short* wp =
                Wr + ((size_t)(tap * 128 + mg * 32 + ln15) * 256 + ic0 + kg * 8);
            a0[tap] = *(const short8*)wp;
            a1[tap] = *(const short8*)(wp + (size_t)16 * 256);
        }
        __builtin_amdgcn_sched_barrier(0);

        if (s < 7) stage((s + 1) & 1, ic0 + 32);
        __builtin_amdgcn_sched_barrier(0);

        // drain stage(s)+A(s); keep stage(s+1) in flight
        if (s < 7) asm volatile("s_waitcnt vmcnt(4)" ::: "memory");
        else       asm volatile("s_waitcnt vmcnt(0)" ::: "memory");
        __builtin_amdgcn_sched_barrier(0);
        __builtin_amdgcn_s_barrier();            // buf[s] staged for all waves
        __builtin_amdgcn_sched_barrier(0);

        const unsigned char* buf = lds + (s & 1) * BUF_BYTES;
        __builtin_amdgcn_s_setprio(1);
        #pragma unroll
        for (int dy = 0; dy < 3; ++dy) {
            #pragma unroll
            for (int dxi = 0; dxi < 3; ++dxi) {
                int tap = dy * 3 + dxi;
                short8 bf[4];
                #pragma unroll
                for (int nt = 0; nt < 4; ++nt) {
                    int col = ng * 64 + nt * 16 + ln15 + dxi;
                    unsigned off =
                        (unsigned)((dy * 130 + col) * 4 + ((kg + SWZ(col)) & 3)) * 16;
                    bf[nt] = *(const short8*)(buf + off);
                }
                #pragma unroll
                for (int nt = 0; nt < 4; ++nt) {
                    acc[0][nt] = __builtin_amdgcn_mfma_f32_16x16x32_bf16(
                        a0[tap], bf[nt], acc[0][nt], 0, 0, 0);
                    acc[1][nt] = __builtin_amdgcn_mfma_f32_16x16x32_bf16(
                        a1[tap], bf[nt], acc[1][nt], 0, 0, 0);
                }
            }
        }
        __builtin_amdgcn_s_setprio(0);
        __builtin_amdgcn_sched_barrier(0);
        __builtin_amdgcn_s_barrier();            // all waves done reading buf[s]
        __builtin_amdgcn_sched_barrier(0);
    }

    // ---- epilogue: refined (bias/BNS/ReLU) -> LDS bf16 [128 oc][stride 130] ----
    unsigned short* refined = (unsigned short*)lds;
    #pragma unroll
    for (int mt = 0; mt < 2; ++mt) {
        #pragma unroll
        for (int nt = 0; nt < 4; ++nt) {
            int px = ng * 64 + nt * 16 + ln15;
            #pragma unroll
            for (int r = 0; r < 4; ++r) {
                int oc = mg * 32 + mt * 16 + kg * 4 + r;   // D: row=(lane>>4)*4+r
                float v = fmaxf((acc[mt][nt][r] + brpn[oc]) * BNS_F, 0.f);
                refined[oc * 130 + px] = f2bf(v);
            }
        }
    }
    __syncthreads();

    // ---- phase 2: z = relu((W_node @ refined + b)*BNS); wave -> 8 dims ----
    float z0[8], z1[8];
    #pragma unroll
    for (int j = 0; j < 8; ++j) { z0[j] = 0.f; z1[j] = 0.f; }
    const float* wn = Wnode + (size_t)wv * 8 * 128;
    for (int k = 0; k < 128; ++k) {
        float r0 = bf2f(refined[k * 130 + lane]);
        float r1 = bf2f(refined[k * 130 + 64 + lane]);
        #pragma unroll
        for (int j = 0; j < 8; ++j) {
            float w = wn[j * 128 + k];
            z0[j] = fmaf(w, r0, z0[j]);
            z1[j] = fmaf(w, r1, z1[j]);
        }
    }
    #pragma unroll
    for (int j = 0; j < 8; ++j) {
        float bb = bnode[wv * 8 + j];
        z0[j] = fmaxf((z0[j] + bb) * BNS_F, 0.f);
        z1[j] = fmaxf((z1[j] + bb) * BNS_F, 0.f);
    }

    // ---- masked accumulation ----
    const float* mrow = masks + ((size_t)b * 12 * 128 + h) * 128;
    float* msb = masked_sum + (size_t)b * 768 + wv * 8;
    for (int c = 0; c < 12; ++c) {
        float m0 = mrow[(size_t)c * 16384 + lane];
        float m1 = mrow[(size_t)c * 16384 + 64 + lane];
        #pragma unroll
        for (int j = 0; j < 8; ++j) {
            float v = fmaf(z0[j], m0, z1[j] * m1);
            #pragma unroll
            for (int off2 = 1; off2 < 64; off2 <<= 1) v += __shfl_xor(v, off2, 64);
            if (lane == 0) atomicAdd(&msb[c * 64 + j], v);
        }
    }
}

// =====================================================================
// graph: node_feats -> edges -> 3-layer GNN -> xs = x_final @ W_sp
// =====================================================================
__global__ __launch_bounds__(256) void graph_kernel(
    const float* __restrict__ masked_sum, const float* __restrict__ mask_sum,
    const float* __restrict__ We1, const float* __restrict__ be1,
    const float* __restrict__ We2, const float* __restrict__ be2,
    const float* __restrict__ Wg, const float* __restrict__ bg,
    const float* __restrict__ lng, const float* __restrict__ lnb,
    const float* __restrict__ glob, const float* __restrict__ Wsp,
    float* __restrict__ xs_out)
{
    __shared__ float nf[12 * 64];
    __shared__ float x [12 * 64];
    __shared__ float xw[12 * 64];
    __shared__ float ea[132 * 64];
    __shared__ float present[12];
    __shared__ float presence[12];

    int b = blockIdx.x;
    int t = threadIdx.x;
    int wv = t >> 6;

    for (int i = t; i < 768; i += 256) {
        float ms = mask_sum[b * 12 + (i >> 6)];
        nf[i] = masked_sum[b * 768 + i] / (ms + 1e-6f);
    }
    if (t < 12) present[t] = (mask_sum[b * 12 + t] > 0.f) ? 1.f : 0.f;
    __syncthreads();

    for (int i = t; i < 768; i += 256) {
        int c = i >> 6;
        float v = nf[i];
        #pragma unroll
        for (int off = 1; off < 64; off <<= 1) v += __shfl_xor(v, off, 64);
        if ((i & 63) == 0) presence[c] = (v != 0.f) ? 1.f : 0.f;
        x[i] = nf[i];
    }
    __syncthreads();

    for (int e = wv; e < 132; e += 4) {
        int src = e / 11;
        int jj = e % 11;
        int dst = jj + (jj >= src ? 1 : 0);
        int d = t & 63;
        float hv = be1[d];
        const float* nsrc = &nf[src * 64];
        const float* ndst = &nf[dst * 64];
        for (int k = 0; k < 64; ++k) hv = fmaf(nsrc[k], We1[k * 64 + d], hv);
        for (int k = 0; k < 64; ++k) hv = fmaf(ndst[k], We1[(64 + k) * 64 + d], hv);
        hv = fmaxf(hv, 0.f);
        float av = be2[d];
        for (int k = 0; k < 64; ++k) {
            float hk = __shfl(hv, k, 64);
            av = fmaf(hk, We2[k * 64 + d], av);
        }
        ea[e * 64 + d] = av * present[src] * present[dst];
    }
    __syncthreads();

    for (int l = 0; l < 3; ++l) {
        const float* wg = Wg + l * 4096;
        for (int i = t; i < 768; i += 256) {
            int c = i >> 6, d = i & 63;
            float v = 0.f;
            for (int k = 0; k < 64; ++k) v = fmaf(x[c * 64 + k], wg[k * 64 + d], v);
            xw[i] = v;
        }
        __syncthreads();
        for (int i = t; i < 768; i += 256) {
            int j = i >> 6, d = i & 63;
            float agg = bg[l * 64 + d];
            #pragma unroll
            for (int src2 = 0; src2 < 12; ++src2) {
                if (src2 == j) continue;
                int jj2 = j - (j > src2 ? 1 : 0);
                int e = src2 * 11 + jj2;
                agg = fmaf(xw[src2 * 64 + d], ea[e * 64 + d], agg);
            }
            float xr = fmaxf(agg, 0.f);
            float s = xr;
            #pragma unroll
            for (int off = 1; off < 64; off <<= 1) s += __shfl_xor(s, off, 64);
            float mu = s * (1.f / 64.f);
            float df = xr - mu;
            float s2 = df * df;
            #pragma unroll
            for (int off = 1; off < 64; off <<= 1) s2 += __shfl_xor(s2, off, 64);
            float var = s2 * (1.f / 64.f);
            float normed = df * (1.0f / sqrtf(var + 1e-5f)) * lng[l * 64 + d]
                           + lnb[l * 64 + d];
            nf[i] = (l > 0) ? (normed + x[i]) : normed;
        }
        __syncthreads();
        for (int i = t; i < 768; i += 256) x[i] = nf[i];
        __syncthreads();
    }

    for (int i = t; i < 768; i += 256) {
        int c = i >> 6;
        float p = presence[c];
        x[i] = x[i] * p + glob[c * 64 + (i & 63)] * (1.f - p);
    }
    __syncthreads();

    for (int i = t; i < 12 * 128; i += 256) {
        int c = i >> 7, o = i & 127;
        float v = 0.f;
        for (int k = 0; k < 64; ++k) v = fmaf(x[c * 64 + k], Wsp[k * 128 + o], v);
        xs_out[b * 1536 + i] = v;
    }
}

// =====================================================================
// out[b,o,h,w] = relu((sum_c xs[b,c,o]*mask[b,c,h,w] + b_sp[o])*BNS)
// =====================================================================
__global__ __launch_bounds__(256) void out_kernel(
    const float* __restrict__ xs, const float* __restrict__ masks,
    const float* __restrict__ bsp, float* __restrict__ out)
{
    __shared__ float xsl[12 * 128];
    __shared__ float ml[12 * 128];
    int bid = blockIdx.x;
    int h = bid & 127;
    int b = bid >> 7;
    int t = threadIdx.x;

    for (int i = t; i < 1536; i += 256) xsl[i] = xs[b * 1536 + i];
    for (int i = t; i < 1536; i += 256) {
        int c = i >> 7, px = i & 127;
        ml[i] = masks[((size_t)(b * 12 + c) * 128 + h) * 128 + px];
    }
    __syncthreads();

    int px = t & 127;
    int og = t >> 7;
    float m[12];
    #pragma unroll
    for (int c = 0; c < 12; ++c) m[c] = ml[c * 128 + px];

    float* ob = out + ((size_t)b * 128 * 128 + h) * 128 + px;
    for (int i = 0; i < 64; ++i) {
        int o = og * 64 + i;
        float s = 0.f;
        #pragma unroll
        for (int c = 0; c < 12; ++c) s = fmaf(xsl[c * 128 + o], m[c], s);
        ob[(size_t)o * 16384] = fmaxf((s + bsp[o]) * BNS_F, 0.f);
    }
}

// =====================================================================
extern "C" void kernel_launch(void* const* d_in, const int* in_sizes, int n_in,
                              void* d_out, int out_size, void* d_ws, size_t ws_size,
                              hipStream_t stream)
{
    const float* feat  = (const float*)d_in[0];
    const float* seg   = (const float*)d_in[1];
    const float* Wrpn  = (const float*)d_in[2];
    const float* brpn  = (const float*)d_in[3];
    const float* Wnode = (const float*)d_in[4];
    const float* bnode = (const float*)d_in[5];
    const float* We1   = (const float*)d_in[6];
    const float* be1   = (const float*)d_in[7];
    const float* We2   = (const float*)d_in[8];
    const float* be2   = (const float*)d_in[9];
    const float* Wg    = (const float*)d_in[10];
    const float* bg    = (const float*)d_in[11];
    const float* lng   = (const float*)d_in[12];
    const float* lnb   = (const float*)d_in[13];
    const float* glob  = (const float*)d_in[14];
    const float* Wsp   = (const float*)d_in[15];
    const float* bsp   = (const float*)d_in[16];
    float* out = (float*)d_out;

    // Fbt (bf16 features, pixel-major) lives in d_out (67.1 MB); fully
    // consumed by conv before out_kernel overwrites it.
    unsigned short* Fbt = (unsigned short*)d_out;

    // workspace (floats): masks | masked_sum | mask_sum | zero16 | xs | Wr(bf16)
    float* masks      = (float*)d_ws;            // 1,572,864
    float* masked_sum = masks + 1572864;         // 6144
    float* mask_sum   = masked_sum + 6144;       // 96
    float* zero16     = mask_sum + 96;           // 8 (16B zero stub)
    float* xs         = zero16 + 8;              // 12288
    unsigned short* Wr = (unsigned short*)(xs + 12288);  // 294,912 bf16

    hipMemsetAsync(masked_sum, 0, (6144 + 96 + 8) * sizeof(float), stream);

    convert_feat<<<2048, 256, 0, stream>>>(feat, Fbt);
    reorg_w<<<128, 256, 0, stream>>>(Wrpn, Wr);
    masks_kernel<<<8 * 12 * 128, 128, 0, stream>>>(seg, masks, mask_sum);
    conv_node_kernel<<<1024, 512, 0, stream>>>(Fbt, Wr, brpn, Wnode, bnode,
                                               masks, zero16, masked_sum);
    graph_kernel<<<8, 256, 0, stream>>>(masked_sum, mask_sum, We1, be1, We2, be2,
                                        Wg, bg, lng, lnb, glob, Wsp, xs);
    out_kernel<<<1024, 256, 0, stream>>>(xs, masks, bsp, out);
}

// Round 5
// 650.566 us; speedup vs baseline: 1.0771x; 1.0771x over previous
//
#include <hip/hip_runtime.h>
#include <math.h>

// B=8, Cin=256, H=W=128, RC=128, NC=12, HD=64, NL=3, E=132
#define BNS_F 0.9999950000374998f

typedef short short8 __attribute__((ext_vector_type(8)));   // 8 bf16 (4 VGPRs)
typedef float f32x4 __attribute__((ext_vector_type(4)));    // MFMA C/D frag
typedef __attribute__((address_space(3))) void lds_void;
typedef const __attribute__((address_space(1))) void glb_void;

__device__ __forceinline__ unsigned short f2bf(float f) {
    unsigned u = __builtin_bit_cast(unsigned, f);
    unsigned r = (u + 0x7fffu + ((u >> 16) & 1u)) >> 16;   // RNE
    return (unsigned short)r;
}
__device__ __forceinline__ float bf2f(unsigned short h) {
    unsigned u = ((unsigned)h) << 16;
    return __builtin_bit_cast(float, u);
}

// =====================================================================
// convert features fp32 [b][ic][px] -> bf16 pixel-major [b][px][ic]
// =====================================================================
__global__ __launch_bounds__(256) void convert_feat(
    const float* __restrict__ feat, unsigned short* __restrict__ Fbt)
{
    __shared__ unsigned short sb[64 * 270];
    int b = blockIdx.x >> 8;
    int px0 = (blockIdx.x & 255) * 64;
    int t = threadIdx.x, l = t & 63, w = t >> 6;

    for (int r = 0; r < 64; ++r) {
        int ic = r * 4 + w;
        float v = feat[((size_t)(b * 256 + ic)) * 16384 + px0 + l];
        sb[l * 270 + ic] = f2bf(v);
    }
    __syncthreads();

    uint4* dst = (uint4*)(Fbt + ((size_t)(b * 16384 + px0)) * 256);
    #pragma unroll
    for (int k = 0; k < 8; ++k) {
        int idx = k * 256 + t;          // uint4 index in [0,2048)
        int px = idx >> 5, piece = idx & 31;
        dst[idx] = *(const uint4*)(sb + px * 270 + piece * 8);
    }
}

// =====================================================================
// reorg W_rpn[oc][ic][tap] fp32 -> Wr[tap][oc][ic] bf16
// =====================================================================
__global__ __launch_bounds__(256) void reorg_w(
    const float* __restrict__ Wrpn, unsigned short* __restrict__ Wr)
{
    int oc = blockIdx.x;            // 128
    int ic = threadIdx.x;           // 256
    const float* src = Wrpn + ((size_t)oc * 256 + ic) * 9;
    #pragma unroll
    for (int tap = 0; tap < 9; ++tap)
        Wr[((size_t)tap * 128 + oc) * 256 + ic] = f2bf(src[tap]);
}

// =====================================================================
// masks = (maxpool3x3(seg) > 0.5), mask_sum[b,c]
// =====================================================================
__global__ __launch_bounds__(128) void masks_kernel(
    const float* __restrict__ seg, float* __restrict__ masks,
    float* __restrict__ mask_sum)
{
    int bid = blockIdx.x;
    int h = bid & 127;
    int c = (bid >> 7) % 12;
    int b = bid / (128 * 12);
    int px = threadIdx.x;

    const float* s = seg + ((size_t)(b * 12 + c) * 128) * 128;
    float m = -INFINITY;
    #pragma unroll
    for (int dy = -1; dy <= 1; ++dy) {
        int y = h + dy;
        if (y < 0 || y > 127) continue;
        #pragma unroll
        for (int dx = -1; dx <= 1; ++dx) {
            int x = px + dx;
            if (x < 0 || x > 127) continue;
            m = fmaxf(m, s[y * 128 + x]);
        }
    }
    float v = (m > 0.5f) ? 1.0f : 0.0f;
    masks[((size_t)(b * 12 + c) * 128 + h) * 128 + px] = v;

    float cnt = v;
    #pragma unroll
    for (int off = 1; off < 64; off <<= 1) cnt += __shfl_xor(cnt, off, 64);
    if ((threadIdx.x & 63) == 0) atomicAdd(&mask_sum[b * 12 + c], cnt);
}

// =====================================================================
// MFMA implicit-GEMM conv + fused 1x1 + masked sums.  v3: occupancy-first.
// grid 2048 = B x H x 2 (px halves), 256 thr = 4 waves.
// Block tile: 128 oc x 64 px; wave wv owns oc [wv*32, wv*32+32).
// LDS 25.3 KB (66-col staging, dbuf) -> up to 6 blocks/CU.
// Plain m97-style loop: prefetch stage(s+1), compute buf(s), __syncthreads.
// =====================================================================
#define SWZ(col) (((col) >> 1) & 3)
#define NCHUNK 792                 // 3 rows * 66 cols * 4 slots
#define BUF_BYTES (NCHUNK * 16)    // 12672

__global__ __launch_bounds__(256) void conv_node_kernel(
    const unsigned short* __restrict__ Fbt, const unsigned short* __restrict__ Wr,
    const float* __restrict__ brpn, const float* __restrict__ Wnode,
    const float* __restrict__ bnode, const float* __restrict__ masks,
    const float* __restrict__ zero16, float* __restrict__ ms_rep)
{
    __shared__ __align__(16) unsigned char lds[2 * BUF_BYTES];   // 25344 B

    // XCD swizzle: 2048 wgs, XCD x gets [x*256, x*256+256) = one batch image
    int wg = blockIdx.x;
    int bid = (wg & 7) * 256 + (wg >> 3);
    int b    = bid >> 8;
    int h    = (bid >> 1) & 127;
    int half = bid & 1;
    int px0  = half * 64;

    int t = threadIdx.x;
    int lane = t & 63;
    int wv = __builtin_amdgcn_readfirstlane(t >> 6);   // 0..3
    int kg = lane >> 4;        // 0..3
    int ln15 = lane & 15;

    f32x4 acc[2][4];
    #pragma unroll
    for (int i = 0; i < 2; ++i)
        #pragma unroll
        for (int j = 0; j < 4; ++j) acc[i][j] = (f32x4){0.f, 0.f, 0.f, 0.f};

    const size_t fb_base = (size_t)b * 16384 * 256;

    // stage 792 chunks of 16B: rounds 0-2 full (256 ea), round 3 = 24 (wave 0)
    auto stage = [&](int bsel, int ic0) {
        #pragma unroll
        for (int r = 0; r < 4; ++r) {
            int c = r * 256 + t;
            bool act = (r < 3) || (t < 24);
            unsigned ldsbase = (unsigned)bsel * BUF_BYTES
                + (unsigned)((r < 3) ? (r * 256 + wv * 64) : 768) * 16;
            if (act) {
                int sp = c & 3, cr = c >> 2;
                int col = cr % 66, row = cr / 66;      // row 0..2
                int sl = (sp - SWZ(col)) & 3;
                int y = h - 1 + row;
                int x = px0 + col - 1;
                const void* gsrc = ((unsigned)y < 128u && (unsigned)x < 128u)
                    ? (const void*)(Fbt + fb_base + (size_t)(y * 128 + x) * 256
                                    + ic0 + sl * 8)
                    : (const void*)zero16;
                __builtin_amdgcn_global_load_lds(
                    (glb_void*)gsrc, (lds_void*)(lds + ldsbase), 16, 0, 0);
            }
        }
    };

    stage(0, 0);
    __syncthreads();

    for (int s = 0; s < 8; ++s) {
        int ic0 = s * 32;
        if (s < 7) stage((s + 1) & 1, ic0 + 32);   // prefetch next chunk

        const unsigned char* buf = lds + (s & 1) * BUF_BYTES;
        #pragma unroll
        for (int dy = 0; dy < 3; ++dy) {
            #pragma unroll
            for (int dxi = 0; dxi < 3; ++dxi) {
                int tap = dy * 3 + dxi;
                const unsigned short* wp =
                    Wr + ((size_t)(tap * 128 + wv * 32 + ln15) * 256 + ic0 + kg * 8);
                short8 a0 = *(const short8*)wp;
                short8 a1 = *(const short8*)(wp + (size_t)16 * 256);
                short8 bf[4];
                #pragma unroll
                for (int nt = 0; nt < 4; ++nt) {
                    int col = nt * 16 + ln15 + dxi;
                    unsigned off =
                        (unsigned)((dy * 66 + col) * 4 + ((kg + SWZ(col)) & 3)) * 16;
                    bf[nt] = *(const short8*)(buf + off);
                }
                #pragma unroll
                for (int nt = 0; nt < 4; ++nt) {
                    acc[0][nt] = __builtin_amdgcn_mfma_f32_16x16x32_bf16(
                        a0, bf[nt], acc[0][nt], 0, 0, 0);
                    acc[1][nt] = __builtin_amdgcn_mfma_f32_16x16x32_bf16(
                        a1, bf[nt], acc[1][nt], 0, 0, 0);
                }
            }
        }
        __syncthreads();   // waves done reading buf(s); prefetch(s+1) landed
    }

    // ---- epilogue: refined (bias/BNS/ReLU) -> LDS bf16 [128 oc][stride 66] ----
    unsigned short* refined = (unsigned short*)lds;
    #pragma unroll
    for (int mt = 0; mt < 2; ++mt) {
        #pragma unroll
        for (int nt = 0; nt < 4; ++nt) {
            int px = nt * 16 + ln15;
            #pragma unroll
            for (int r = 0; r < 4; ++r) {
                int oc = wv * 32 + mt * 16 + kg * 4 + r;   // D: row=(lane>>4)*4+r
                float v = fmaxf((acc[mt][nt][r] + brpn[oc]) * BNS_F, 0.f);
                refined[oc * 66 + px] = f2bf(v);
            }
        }
    }
    __syncthreads();

    // ---- phase 2: z = relu((W_node @ refined + b)*BNS); wave -> 16 dims ----
    float z[16];
    #pragma unroll
    for (int j = 0; j < 16; ++j) z[j] = 0.f;
    const float* wn = Wnode + (size_t)wv * 16 * 128;
    for (int k = 0; k < 128; ++k) {
        float rv = bf2f(refined[k * 66 + lane]);
        #pragma unroll
        for (int j = 0; j < 16; ++j)
            z[j] = fmaf(wn[j * 128 + k], rv, z[j]);
    }
    #pragma unroll
    for (int j = 0; j < 16; ++j)
        z[j] = fmaxf((z[j] + bnode[wv * 16 + j]) * BNS_F, 0.f);

    // ---- masked accumulation into replica rep = bid&7 ----
    int rep = bid & 7;
    const float* mrow = masks + ((size_t)b * 12 * 128 + h) * 128 + px0;
    float* msb = ms_rep + ((size_t)(rep * 8 + b) * 12) * 64 + wv * 16;
    for (int c = 0; c < 12; ++c) {
        float m = mrow[(size_t)c * 16384 + lane];
        #pragma unroll
        for (int j = 0; j < 16; ++j) {
            float v = z[j] * m;
            #pragma unroll
            for (int off2 = 1; off2 < 64; off2 <<= 1) v += __shfl_xor(v, off2, 64);
            if (lane == j) atomicAdd(&msb[c * 64 + j], v);
        }
    }
}

// =====================================================================
// edge MLP: 264 blocks = 8 b x 33 edge-groups; wave = one edge
// =====================================================================
__global__ __launch_bounds__(256) void edge_kernel(
    const float* __restrict__ ms_rep, const float* __restrict__ mask_sum,
    const float* __restrict__ We1, const float* __restrict__ be1,
    const float* __restrict__ We2, const float* __restrict__ be2,
    float* __restrict__ ea_g)
{
    int gb = blockIdx.x;
    int b = gb / 33, eg = gb % 33;
    int wv = threadIdx.x >> 6, d = threadIdx.x & 63;
    int e = eg * 4 + wv;                    // 0..131
    int src = e / 11, jj = e % 11;
    int dst = jj + (jj >= src ? 1 : 0);

    float mssrc = 0.f, msdst = 0.f;
    #pragma unroll
    for (int rep = 0; rep < 8; ++rep) {
        mssrc += ms_rep[((size_t)(rep * 8 + b) * 12 + src) * 64 + d];
        msdst += ms_rep[((size_t)(rep * 8 + b) * 12 + dst) * 64 + d];
    }
    float cs = mask_sum[b * 12 + src], cd = mask_sum[b * 12 + dst];
    float nsrc = mssrc / (cs + 1e-6f);
    float ndst = msdst / (cd + 1e-6f);

    float hv = be1[d];
    for (int k = 0; k < 64; ++k) hv = fmaf(__shfl(nsrc, k, 64), We1[k * 64 + d], hv);
    for (int k = 0; k < 64; ++k) hv = fmaf(__shfl(ndst, k, 64), We1[(64 + k) * 64 + d], hv);
    hv = fmaxf(hv, 0.f);
    float av = be2[d];
    for (int k = 0; k < 64; ++k) av = fmaf(__shfl(hv, k, 64), We2[k * 64 + d], av);

    float valid = ((cs > 0.f) ? 1.f : 0.f) * ((cd > 0.f) ? 1.f : 0.f);
    ea_g[((size_t)b * 132 + e) * 64 + d] = av * valid;
}

// =====================================================================
// graph: node_feats -> 3-layer GNN -> xs = x_final @ W_sp  (8 blocks)
// =====================================================================
__global__ __launch_bounds__(256) void graph_kernel(
    const float* __restrict__ ms_rep, const float* __restrict__ mask_sum,
    const float* __restrict__ ea_g,
    const float* __restrict__ Wg, const float* __restrict__ bg,
    const float* __restrict__ lng, const float* __restrict__ lnb,
    const float* __restrict__ glob, const float* __restrict__ Wsp,
    float* __restrict__ xs_out)
{
    __shared__ float nf[12 * 64];
    __shared__ float x [12 * 64];
    __shared__ float xw[12 * 64];
    __shared__ float ea[132 * 64];
    __shared__ float presence[12];

    int b = blockIdx.x;
    int t = threadIdx.x;

    for (int i = t; i < 768; i += 256) {
        int c = i >> 6, d = i & 63;
        float ms = 0.f;
        #pragma unroll
        for (int rep = 0; rep < 8; ++rep)
            ms += ms_rep[((size_t)(rep * 8 + b) * 12 + c) * 64 + d];
        nf[i] = ms / (mask_sum[b * 12 + c] + 1e-6f);
    }
    for (int i = t; i < 132 * 64; i += 256) ea[i] = ea_g[(size_t)b * 8448 + i];
    __syncthreads();

    for (int i = t; i < 768; i += 256) {
        int c = i >> 6;
        float v = nf[i];
        #pragma unroll
        for (int off = 1; off < 64; off <<= 1) v += __shfl_xor(v, off, 64);
        if ((i & 63) == 0) presence[c] = (v != 0.f) ? 1.f : 0.f;
        x[i] = nf[i];
    }
    __syncthreads();

    for (int l = 0; l < 3; ++l) {
        const float* wg = Wg + l * 4096;
        for (int i = t; i < 768; i += 256) {
            int c = i >> 6, d = i & 63;
            float v = 0.f;
            for (int k = 0; k < 64; ++k) v = fmaf(x[c * 64 + k], wg[k * 64 + d], v);
            xw[i] = v;
        }
        __syncthreads();
        for (int i = t; i < 768; i += 256) {
            int j = i >> 6, d = i & 63;
            float agg = bg[l * 64 + d];
            #pragma unroll
            for (int src2 = 0; src2 < 12; ++src2) {
                if (src2 == j) continue;
                int jj2 = j - (j > src2 ? 1 : 0);
                int e = src2 * 11 + jj2;
                agg = fmaf(xw[src2 * 64 + d], ea[e * 64 + d], agg);
            }
            float xr = fmaxf(agg, 0.f);
            float s = xr;
            #pragma unroll
            for (int off = 1; off < 64; off <<= 1) s += __shfl_xor(s, off, 64);
            float mu = s * (1.f / 64.f);
            float df = xr - mu;
            float s2 = df * df;
            #pragma unroll
            for (int off = 1; off < 64; off <<= 1) s2 += __shfl_xor(s2, off, 64);
            float var = s2 * (1.f / 64.f);
            float normed = df * (1.0f / sqrtf(var + 1e-5f)) * lng[l * 64 + d]
                           + lnb[l * 64 + d];
            nf[i] = (l > 0) ? (normed + x[i]) : normed;
        }
        __syncthreads();
        for (int i = t; i < 768; i += 256) x[i] = nf[i];
        __syncthreads();
    }

    for (int i = t; i < 768; i += 256) {
        int c = i >> 6;
        float p = presence[c];
        x[i] = x[i] * p + glob[c * 64 + (i & 63)] * (1.f - p);
    }
    __syncthreads();

    for (int i = t; i < 12 * 128; i += 256) {
        int c = i >> 7, o = i & 127;
        float v = 0.f;
        for (int k = 0; k < 64; ++k) v = fmaf(x[c * 64 + k], Wsp[k * 128 + o], v);
        xs_out[b * 1536 + i] = v;
    }
}

// =====================================================================
// out[b,o,h,w] = relu((sum_c xs[b,c,o]*mask[b,c,h,w] + b_sp[o])*BNS)
// =====================================================================
__global__ __launch_bounds__(256) void out_kernel(
    const float* __restrict__ xs, const float* __restrict__ masks,
    const float* __restrict__ bsp, float* __restrict__ out)
{
    __shared__ float xsl[12 * 128];
    __shared__ float ml[12 * 128];
    int bid = blockIdx.x;
    int h = bid & 127;
    int b = bid >> 7;
    int t = threadIdx.x;

    for (int i = t; i < 1536; i += 256) xsl[i] = xs[b * 1536 + i];
    for (int i = t; i < 1536; i += 256) {
        int c = i >> 7, px = i & 127;
        ml[i] = masks[((size_t)(b * 12 + c) * 128 + h) * 128 + px];
    }
    __syncthreads();

    int px = t & 127;
    int og = t >> 7;
    float m[12];
    #pragma unroll
    for (int c = 0; c < 12; ++c) m[c] = ml[c * 128 + px];

    float* ob = out + ((size_t)b * 128 * 128 + h) * 128 + px;
    for (int i = 0; i < 64; ++i) {
        int o = og * 64 + i;
        float s = 0.f;
        #pragma unroll
        for (int c = 0; c < 12; ++c) s = fmaf(xsl[c * 128 + o], m[c], s);
        ob[(size_t)o * 16384] = fmaxf((s + bsp[o]) * BNS_F, 0.f);
    }
}

// =====================================================================
extern "C" void kernel_launch(void* const* d_in, const int* in_sizes, int n_in,
                              void* d_out, int out_size, void* d_ws, size_t ws_size,
                              hipStream_t stream)
{
    const float* feat  = (const float*)d_in[0];
    const float* seg   = (const float*)d_in[1];
    const float* Wrpn  = (const float*)d_in[2];
    const float* brpn  = (const float*)d_in[3];
    const float* Wnode = (const float*)d_in[4];
    const float* bnode = (const float*)d_in[5];
    const float* We1   = (const float*)d_in[6];
    const float* be1   = (const float*)d_in[7];
    const float* We2   = (const float*)d_in[8];
    const float* be2   = (const float*)d_in[9];
    const float* Wg    = (const float*)d_in[10];
    const float* bg    = (const float*)d_in[11];
    const float* lng   = (const float*)d_in[12];
    const float* lnb   = (const float*)d_in[13];
    const float* glob  = (const float*)d_in[14];
    const float* Wsp   = (const float*)d_in[15];
    const float* bsp   = (const float*)d_in[16];
    float* out = (float*)d_out;

    // Fbt (bf16 features, pixel-major) lives in d_out (67.1 MB); fully
    // consumed by conv before out_kernel overwrites it.
    unsigned short* Fbt = (unsigned short*)d_out;

    // workspace (floats):
    float* masks    = (float*)d_ws;              // 1,572,864
    float* ms_rep   = masks + 1572864;           // 8*8*12*64 = 49,152
    float* mask_sum = ms_rep + 49152;            // 96
    float* zero16   = mask_sum + 96;             // 8 (16B zero stub)
    float* xs       = zero16 + 8;                // 12,288
    float* ea_g     = xs + 12288;                // 8*132*64 = 67,584
    unsigned short* Wr = (unsigned short*)(ea_g + 67584);  // 294,912 bf16

    hipMemsetAsync(ms_rep, 0, (49152 + 96 + 8) * sizeof(float), stream);

    convert_feat<<<2048, 256, 0, stream>>>(feat, Fbt);
    reorg_w<<<128, 256, 0, stream>>>(Wrpn, Wr);
    masks_kernel<<<8 * 12 * 128, 128, 0, stream>>>(seg, masks, mask_sum);
    conv_node_kernel<<<2048, 256, 0, stream>>>(Fbt, Wr, brpn, Wnode, bnode,
                                               masks, zero16, ms_rep);
    edge_kernel<<<264, 256, 0, stream>>>(ms_rep, mask_sum, We1, be1, We2, be2, ea_g);
    graph_kernel<<<8, 256, 0, stream>>>(ms_rep, mask_sum, ea_g,
                                        Wg, bg, lng, lnb, glob, Wsp, xs);
    out_kernel<<<1024, 256, 0, stream>>>(xs, masks, bsp, out);
}

// Round 6
// 455.887 us; speedup vs baseline: 1.5370x; 1.4270x over previous
//
#include <hip/hip_runtime.h>
#include <math.h>

// B=8, Cin=256, H=W=128, RC=128, NC=12, HD=64, NL=3, E=132
#define BNS_F 0.9999950000374998f

typedef short short8 __attribute__((ext_vector_type(8)));   // 8 bf16 (4 VGPRs)
typedef float f32x4 __attribute__((ext_vector_type(4)));    // MFMA C/D frag
typedef __attribute__((address_space(3))) void lds_void;
typedef const __attribute__((address_space(1))) void glb_void;

__device__ __forceinline__ unsigned short f2bf(float f) {
    unsigned u = __builtin_bit_cast(unsigned, f);
    unsigned r = (u + 0x7fffu + ((u >> 16) & 1u)) >> 16;   // RNE
    return (unsigned short)r;
}
__device__ __forceinline__ float bf2f(unsigned short h) {
    unsigned u = ((unsigned)h) << 16;
    return __builtin_bit_cast(float, u);
}

// =====================================================================
// convert features fp32 [b][ic][px] -> bf16 pixel-major [b][px][ic]
// =====================================================================
__global__ __launch_bounds__(256) void convert_feat(
    const float* __restrict__ feat, unsigned short* __restrict__ Fbt)
{
    __shared__ unsigned short sb[64 * 270];
    int b = blockIdx.x >> 8;
    int px0 = (blockIdx.x & 255) * 64;
    int t = threadIdx.x, l = t & 63, w = t >> 6;

    for (int r = 0; r < 64; ++r) {
        int ic = r * 4 + w;
        float v = feat[((size_t)(b * 256 + ic)) * 16384 + px0 + l];
        sb[l * 270 + ic] = f2bf(v);
    }
    __syncthreads();

    uint4* dst = (uint4*)(Fbt + ((size_t)(b * 16384 + px0)) * 256);
    #pragma unroll
    for (int k = 0; k < 8; ++k) {
        int idx = k * 256 + t;          // uint4 index in [0,2048)
        int px = idx >> 5, piece = idx & 31;
        dst[idx] = *(const uint4*)(sb + px * 270 + piece * 8);
    }
}

// =====================================================================
// reorg W_rpn[oc][ic][tap] fp32 -> Wr[tap][oc][ic] bf16
// =====================================================================
__global__ __launch_bounds__(256) void reorg_w(
    const float* __restrict__ Wrpn, unsigned short* __restrict__ Wr)
{
    int oc = blockIdx.x;            // 128
    int ic = threadIdx.x;           // 256
    const float* src = Wrpn + ((size_t)oc * 256 + ic) * 9;
    #pragma unroll
    for (int tap = 0; tap < 9; ++tap)
        Wr[((size_t)tap * 128 + oc) * 256 + ic] = f2bf(src[tap]);
}

// =====================================================================
// masks = (maxpool3x3(seg) > 0.5), mask_sum[b,c]
// =====================================================================
__global__ __launch_bounds__(128) void masks_kernel(
    const float* __restrict__ seg, float* __restrict__ masks,
    float* __restrict__ mask_sum)
{
    int bid = blockIdx.x;
    int h = bid & 127;
    int c = (bid >> 7) % 12;
    int b = bid / (128 * 12);
    int px = threadIdx.x;

    const float* s = seg + ((size_t)(b * 12 + c) * 128) * 128;
    float m = -INFINITY;
    #pragma unroll
    for (int dy = -1; dy <= 1; ++dy) {
        int y = h + dy;
        if (y < 0 || y > 127) continue;
        #pragma unroll
        for (int dx = -1; dx <= 1; ++dx) {
            int x = px + dx;
            if (x < 0 || x > 127) continue;
            m = fmaxf(m, s[y * 128 + x]);
        }
    }
    float v = (m > 0.5f) ? 1.0f : 0.0f;
    masks[((size_t)(b * 12 + c) * 128 + h) * 128 + px] = v;

    float cnt = v;
    #pragma unroll
    for (int off = 1; off < 64; off <<= 1) cnt += __shfl_xor(cnt, off, 64);
    if ((threadIdx.x & 63) == 0) atomicAdd(&mask_sum[b * 12 + c], cnt);
}

// =====================================================================
// MFMA implicit-GEMM conv + fused 1x1 + masked sums.  v4: R2 structure
// (best measured: 380us @ 42% occ, VGPR 52) + LDS trim (3 blocks/CU)
// + XCD swizzle + stage-after-compute (zero-VGPR FIFO decoupling).
// grid 1024 = B x H, 512 thr = 8 waves; wave (mg,ng): 32 oc x 64 px.
// =====================================================================
#define SWZ(col) (((col) >> 1) & 3)
#define BUF_BYTES 24960   // 1560 chunks * 16B (3 rows * 130 cols * 4 slots)

__global__ __launch_bounds__(512) void conv_node_kernel(
    const unsigned short* __restrict__ Fbt, const unsigned short* __restrict__ Wr,
    const float* __restrict__ brpn, const float* __restrict__ Wnode,
    const float* __restrict__ bnode, const float* __restrict__ masks,
    const float* __restrict__ zero16, float* __restrict__ ms_rep)
{
    __shared__ __align__(16) unsigned char lds[49920];  // 2 staging bufs; epilogue reuses

    // XCD swizzle: 1024 wgs, XCD x gets logical blocks [x*128, x*128+128) = batch x
    int wg = blockIdx.x;
    int bid = (wg & 7) * 128 + (wg >> 3);
    int h = bid & 127, b = bid >> 7;

    int t = threadIdx.x;
    int lane = t & 63;
    int wv = __builtin_amdgcn_readfirstlane(t >> 6);  // 0..7 wave-uniform
    int mg = wv >> 1;        // oc0 = mg*32
    int ng = wv & 1;         // px0 = ng*64
    int kg = lane >> 4;      // 0..3
    int ln15 = lane & 15;

    f32x4 acc[2][4];
    #pragma unroll
    for (int i = 0; i < 2; ++i)
        #pragma unroll
        for (int j = 0; j < 4; ++j) acc[i][j] = (f32x4){0.f, 0.f, 0.f, 0.f};

    const size_t fb_base = (size_t)b * 16384 * 256;

    // stage 1560 chunks of 16B: 3 rounds of 512 + 24 extra (wave 0)
    auto stage = [&](int bsel, int ic0) {
        for (int c0 = 0; c0 < 1560; c0 += 512) {
            int c = c0 + t;
            unsigned ldsoff = (unsigned)bsel * BUF_BYTES + (unsigned)(c0 + wv * 64) * 16;
            if (c < 1560) {
                int sp = c & 3, cr = c >> 2;
                int col = cr % 130, row = cr / 130;     // row 0..2, y = h-1+row
                int sl = (sp - SWZ(col)) & 3;           // logical slot -> ic offset
                int y = h - 1 + row;
                int x = col - 1;
                const void* gsrc = ((unsigned)y < 128u && (unsigned)x < 128u)
                    ? (const void*)(Fbt + fb_base + (size_t)(y * 128 + x) * 256
                                    + ic0 + sl * 8)
                    : (const void*)zero16;
                __builtin_amdgcn_global_load_lds(
                    (glb_void*)gsrc, (lds_void*)(lds + ldsoff), 16, 0, 0);
            }
        }
    };

    stage(0, 0);
    __syncthreads();

    for (int s = 0; s < 8; ++s) {
        int ic0 = s * 32;
        const unsigned char* buf = lds + (s & 1) * BUF_BYTES;

        // ---- compute chunk s (A-loads inline; issued before stage(s+1)) ----
        #pragma unroll
        for (int dy = 0; dy < 3; ++dy) {
            #pragma unroll
            for (int dxi = 0; dxi < 3; ++dxi) {
                int tap = dy * 3 + dxi;
                const unsigned short* wp =
                    Wr + ((size_t)(tap * 128 + mg * 32 + ln15) * 256 + ic0 + kg * 8);
                short8 a0 = *(const short8*)wp;
                short8 a1 = *(const short8*)(wp + (size_t)16 * 256);
                short8 bf[4];
                #pragma unroll
                for (int nt = 0; nt < 4; ++nt) {
                    int col = ng * 64 + nt * 16 + ln15 + dxi;
                    unsigned off =
                        (unsigned)((dy * 130 + col) * 4 + ((kg + SWZ(col)) & 3)) * 16;
                    bf[nt] = *(const short8*)(buf + off);
                }
                #pragma unroll
                for (int nt = 0; nt < 4; ++nt) {
                    acc[0][nt] = __builtin_amdgcn_mfma_f32_16x16x32_bf16(
                        a0, bf[nt], acc[0][nt], 0, 0, 0);
                    acc[1][nt] = __builtin_amdgcn_mfma_f32_16x16x32_bf16(
                        a1, bf[nt], acc[1][nt], 0, 0, 0);
                }
            }
        }

        // ---- prefetch next chunk AFTER compute-issue; lands at the barrier ----
        if (s < 7) stage((s + 1) & 1, ic0 + 32);
        __syncthreads();
    }

    // ---- epilogue: refined (bias/BNS/ReLU) -> LDS bf16 [128 oc][stride 130] ----
    unsigned short* refined = (unsigned short*)lds;
    #pragma unroll
    for (int mt = 0; mt < 2; ++mt) {
        #pragma unroll
        for (int nt = 0; nt < 4; ++nt) {
            int px = ng * 64 + nt * 16 + ln15;
            #pragma unroll
            for (int r = 0; r < 4; ++r) {
                int oc = mg * 32 + mt * 16 + kg * 4 + r;   // D: row=(lane>>4)*4+r
                float v = fmaxf((acc[mt][nt][r] + brpn[oc]) * BNS_F, 0.f);
                refined[oc * 130 + px] = f2bf(v);
            }
        }
    }
    __syncthreads();

    // ---- phase 2: z = relu((W_node @ refined + b)*BNS); wave -> 8 dims ----
    float z0[8], z1[8];
    #pragma unroll
    for (int j = 0; j < 8; ++j) { z0[j] = 0.f; z1[j] = 0.f; }
    const float* wn = Wnode + (size_t)wv * 8 * 128;
    for (int k = 0; k < 128; ++k) {
        float r0 = bf2f(refined[k * 130 + lane]);
        float r1 = bf2f(refined[k * 130 + 64 + lane]);
        #pragma unroll
        for (int j = 0; j < 8; ++j) {
            float w = wn[j * 128 + k];
            z0[j] = fmaf(w, r0, z0[j]);
            z1[j] = fmaf(w, r1, z1[j]);
        }
    }
    #pragma unroll
    for (int j = 0; j < 8; ++j) {
        float bb = bnode[wv * 8 + j];
        z0[j] = fmaxf((z0[j] + bb) * BNS_F, 0.f);
        z1[j] = fmaxf((z1[j] + bb) * BNS_F, 0.f);
    }

    // ---- masked accumulation into replica rep = h&7 ----
    int rep = bid & 7;
    const float* mrow = masks + ((size_t)b * 12 * 128 + h) * 128;
    float* msb = ms_rep + ((size_t)(rep * 8 + b) * 12) * 64 + wv * 8;
    for (int c = 0; c < 12; ++c) {
        float m0 = mrow[(size_t)c * 16384 + lane];
        float m1 = mrow[(size_t)c * 16384 + 64 + lane];
        #pragma unroll
        for (int j = 0; j < 8; ++j) {
            float v = fmaf(z0[j], m0, z1[j] * m1);
            #pragma unroll
            for (int off2 = 1; off2 < 64; off2 <<= 1) v += __shfl_xor(v, off2, 64);
            if (lane == 0) atomicAdd(&msb[c * 64 + j], v);
        }
    }
}

// =====================================================================
// edge MLP: 264 blocks = 8 b x 33 edge-groups; wave = one edge
// =====================================================================
__global__ __launch_bounds__(256) void edge_kernel(
    const float* __restrict__ ms_rep, const float* __restrict__ mask_sum,
    const float* __restrict__ We1, const float* __restrict__ be1,
    const float* __restrict__ We2, const float* __restrict__ be2,
    float* __restrict__ ea_g)
{
    int gb = blockIdx.x;
    int b = gb / 33, eg = gb % 33;
    int wv = threadIdx.x >> 6, d = threadIdx.x & 63;
    int e = eg * 4 + wv;                    // 0..131
    int src = e / 11, jj = e % 11;
    int dst = jj + (jj >= src ? 1 : 0);

    float mssrc = 0.f, msdst = 0.f;
    #pragma unroll
    for (int rep = 0; rep < 8; ++rep) {
        mssrc += ms_rep[((size_t)(rep * 8 + b) * 12 + src) * 64 + d];
        msdst += ms_rep[((size_t)(rep * 8 + b) * 12 + dst) * 64 + d];
    }
    float cs = mask_sum[b * 12 + src], cd = mask_sum[b * 12 + dst];
    float nsrc = mssrc / (cs + 1e-6f);
    float ndst = msdst / (cd + 1e-6f);

    float hv = be1[d];
    for (int k = 0; k < 64; ++k) hv = fmaf(__shfl(nsrc, k, 64), We1[k * 64 + d], hv);
    for (int k = 0; k < 64; ++k) hv = fmaf(__shfl(ndst, k, 64), We1[(64 + k) * 64 + d], hv);
    hv = fmaxf(hv, 0.f);
    float av = be2[d];
    for (int k = 0; k < 64; ++k) av = fmaf(__shfl(hv, k, 64), We2[k * 64 + d], av);

    float valid = ((cs > 0.f) ? 1.f : 0.f) * ((cd > 0.f) ? 1.f : 0.f);
    ea_g[((size_t)b * 132 + e) * 64 + d] = av * valid;
}

// =====================================================================
// graph: node_feats -> 3-layer GNN -> xs = x_final @ W_sp  (8 blocks)
// =====================================================================
__global__ __launch_bounds__(256) void graph_kernel(
    const float* __restrict__ ms_rep, const float* __restrict__ mask_sum,
    const float* __restrict__ ea_g,
    const float* __restrict__ Wg, const float* __restrict__ bg,
    const float* __restrict__ lng, const float* __restrict__ lnb,
    const float* __restrict__ glob, const float* __restrict__ Wsp,
    float* __restrict__ xs_out)
{
    __shared__ float nf[12 * 64];
    __shared__ float x [12 * 64];
    __shared__ float xw[12 * 64];
    __shared__ float ea[132 * 64];
    __shared__ float presence[12];

    int b = blockIdx.x;
    int t = threadIdx.x;

    for (int i = t; i < 768; i += 256) {
        int c = i >> 6, d = i & 63;
        float ms = 0.f;
        #pragma unroll
        for (int rep = 0; rep < 8; ++rep)
            ms += ms_rep[((size_t)(rep * 8 + b) * 12 + c) * 64 + d];
        nf[i] = ms / (mask_sum[b * 12 + c] + 1e-6f);
    }
    for (int i = t; i < 132 * 64; i += 256) ea[i] = ea_g[(size_t)b * 8448 + i];
    __syncthreads();

    for (int i = t; i < 768; i += 256) {
        int c = i >> 6;
        float v = nf[i];
        #pragma unroll
        for (int off = 1; off < 64; off <<= 1) v += __shfl_xor(v, off, 64);
        if ((i & 63) == 0) presence[c] = (v != 0.f) ? 1.f : 0.f;
        x[i] = nf[i];
    }
    __syncthreads();

    for (int l = 0; l < 3; ++l) {
        const float* wg = Wg + l * 4096;
        for (int i = t; i < 768; i += 256) {
            int c = i >> 6, d = i & 63;
            float v = 0.f;
            for (int k = 0; k < 64; ++k) v = fmaf(x[c * 64 + k], wg[k * 64 + d], v);
            xw[i] = v;
        }
        __syncthreads();
        for (int i = t; i < 768; i += 256) {
            int j = i >> 6, d = i & 63;
            float agg = bg[l * 64 + d];
            #pragma unroll
            for (int src2 = 0; src2 < 12; ++src2) {
                if (src2 == j) continue;
                int jj2 = j - (j > src2 ? 1 : 0);
                int e = src2 * 11 + jj2;
                agg = fmaf(xw[src2 * 64 + d], ea[e * 64 + d], agg);
            }
            float xr = fmaxf(agg, 0.f);
            float s = xr;
            #pragma unroll
            for (int off = 1; off < 64; off <<= 1) s += __shfl_xor(s, off, 64);
            float mu = s * (1.f / 64.f);
            float df = xr - mu;
            float s2 = df * df;
            #pragma unroll
            for (int off = 1; off < 64; off <<= 1) s2 += __shfl_xor(s2, off, 64);
            float var = s2 * (1.f / 64.f);
            float normed = df * (1.0f / sqrtf(var + 1e-5f)) * lng[l * 64 + d]
                           + lnb[l * 64 + d];
            nf[i] = (l > 0) ? (normed + x[i]) : normed;
        }
        __syncthreads();
        for (int i = t; i < 768; i += 256) x[i] = nf[i];
        __syncthreads();
    }

    for (int i = t; i < 768; i += 256) {
        int c = i >> 6;
        float p = presence[c];
        x[i] = x[i] * p + glob[c * 64 + (i & 63)] * (1.f - p);
    }
    __syncthreads();

    for (int i = t; i < 12 * 128; i += 256) {
        int c = i >> 7, o = i & 127;
        float v = 0.f;
        for (int k = 0; k < 64; ++k) v = fmaf(x[c * 64 + k], Wsp[k * 128 + o], v);
        xs_out[b * 1536 + i] = v;
    }
}

// =====================================================================
// out[b,o,h,w] = relu((sum_c xs[b,c,o]*mask[b,c,h,w] + b_sp[o])*BNS)
// =====================================================================
__global__ __launch_bounds__(256) void out_kernel(
    const float* __restrict__ xs, const float* __restrict__ masks,
    const float* __restrict__ bsp, float* __restrict__ out)
{
    __shared__ float xsl[12 * 128];
    __shared__ float ml[12 * 128];
    int bid = blockIdx.x;
    int h = bid & 127;
    int b = bid >> 7;
    int t = threadIdx.x;

    for (int i = t; i < 1536; i += 256) xsl[i] = xs[b * 1536 + i];
    for (int i = t; i < 1536; i += 256) {
        int c = i >> 7, px = i & 127;
        ml[i] = masks[((size_t)(b * 12 + c) * 128 + h) * 128 + px];
    }
    __syncthreads();

    int px = t & 127;
    int og = t >> 7;
    float m[12];
    #pragma unroll
    for (int c = 0; c < 12; ++c) m[c] = ml[c * 128 + px];

    float* ob = out + ((size_t)b * 128 * 128 + h) * 128 + px;
    for (int i = 0; i < 64; ++i) {
        int o = og * 64 + i;
        float s = 0.f;
        #pragma unroll
        for (int c = 0; c < 12; ++c) s = fmaf(xsl[c * 128 + o], m[c], s);
        ob[(size_t)o * 16384] = fmaxf((s + bsp[o]) * BNS_F, 0.f);
    }
}

// =====================================================================
extern "C" void kernel_launch(void* const* d_in, const int* in_sizes, int n_in,
                              void* d_out, int out_size, void* d_ws, size_t ws_size,
                              hipStream_t stream)
{
    const float* feat  = (const float*)d_in[0];
    const float* seg   = (const float*)d_in[1];
    const float* Wrpn  = (const float*)d_in[2];
    const float* brpn  = (const float*)d_in[3];
    const float* Wnode = (const float*)d_in[4];
    const float* bnode = (const float*)d_in[5];
    const float* We1   = (const float*)d_in[6];
    const float* be1   = (const float*)d_in[7];
    const float* We2   = (const float*)d_in[8];
    const float* be2   = (const float*)d_in[9];
    const float* Wg    = (const float*)d_in[10];
    const float* bg    = (const float*)d_in[11];
    const float* lng   = (const float*)d_in[12];
    const float* lnb   = (const float*)d_in[13];
    const float* glob  = (const float*)d_in[14];
    const float* Wsp   = (const float*)d_in[15];
    const float* bsp   = (const float*)d_in[16];
    float* out = (float*)d_out;

    // Fbt (bf16 features, pixel-major) lives in d_out (67.1 MB); fully
    // consumed by conv before out_kernel overwrites it.
    unsigned short* Fbt = (unsigned short*)d_out;

    // workspace (floats):
    float* masks    = (float*)d_ws;              // 1,572,864
    float* ms_rep   = masks + 1572864;           // 8*8*12*64 = 49,152
    float* mask_sum = ms_rep + 49152;            // 96
    float* zero16   = mask_sum + 96;             // 8 (16B zero stub)
    float* xs       = zero16 + 8;                // 12,288
    float* ea_g     = xs + 12288;                // 8*132*64 = 67,584
    unsigned short* Wr = (unsigned short*)(ea_g + 67584);  // 294,912 bf16

    hipMemsetAsync(ms_rep, 0, (49152 + 96 + 8) * sizeof(float), stream);

    convert_feat<<<2048, 256, 0, stream>>>(feat, Fbt);
    reorg_w<<<128, 256, 0, stream>>>(Wrpn, Wr);
    masks_kernel<<<8 * 12 * 128, 128, 0, stream>>>(seg, masks, mask_sum);
    conv_node_kernel<<<1024, 512, 0, stream>>>(Fbt, Wr, brpn, Wnode, bnode,
                                               masks, zero16, ms_rep);
    edge_kernel<<<264, 256, 0, stream>>>(ms_rep, mask_sum, We1, be1, We2, be2, ea_g);
    graph_kernel<<<8, 256, 0, stream>>>(ms_rep, mask_sum, ea_g,
                                        Wg, bg, lng, lnb, glob, Wsp, xs);
    out_kernel<<<1024, 256, 0, stream>>>(xs, masks, bsp, out);
}